// Round 11
// baseline (1888.047 us; speedup 1.0000x reference)
//
#include <hip/hip_runtime.h>
#include <float.h>

#define N_TOK 262144
#define N_E   1024
#define E_DIM 64
#define BETA  0.25f
#define BLK   256      // 128 tokens x 2 j-halves per block
#define TPB   128      // tokens per block
#define JSPL  512      // j's per half

typedef float f32x64 __attribute__((ext_vector_type(64)));

// ---------------------------------------------------------------------------
// Bit-exact replica of numpy f32 sum-of-squares over 64 elements.
// numpy reduce: out = q0 + pairwise_sum(q[1:], 63):
//   r[i] = b[i] (i=0..7); for blk=8..48 step 8: r[i] += b[blk+i];
//   res = ((r0+r1)+(r2+r3))+((r4+r5)+(r6+r7)); res += b[56..62] seq;
//   out = q0 + res;   (b[i] = v[1+i], all ops individually rounded)
// DO NOT change the op order: index bit-exactness depends on it.
// ---------------------------------------------------------------------------
__device__ __forceinline__ float np_sumsq64_v(f32x64 v)
{
    float r0 = __fmul_rn(v[1], v[1]);
    float r1 = __fmul_rn(v[2], v[2]);
    float r2 = __fmul_rn(v[3], v[3]);
    float r3 = __fmul_rn(v[4], v[4]);
    float r4 = __fmul_rn(v[5], v[5]);
    float r5 = __fmul_rn(v[6], v[6]);
    float r6 = __fmul_rn(v[7], v[7]);
    float r7 = __fmul_rn(v[8], v[8]);
#define VQ_ACC8(blk)                                                     \
    r0 = __fadd_rn(r0, __fmul_rn(v[1 + (blk)], v[1 + (blk)]));          \
    r1 = __fadd_rn(r1, __fmul_rn(v[2 + (blk)], v[2 + (blk)]));          \
    r2 = __fadd_rn(r2, __fmul_rn(v[3 + (blk)], v[3 + (blk)]));          \
    r3 = __fadd_rn(r3, __fmul_rn(v[4 + (blk)], v[4 + (blk)]));          \
    r4 = __fadd_rn(r4, __fmul_rn(v[5 + (blk)], v[5 + (blk)]));          \
    r5 = __fadd_rn(r5, __fmul_rn(v[6 + (blk)], v[6 + (blk)]));          \
    r6 = __fadd_rn(r6, __fmul_rn(v[7 + (blk)], v[7 + (blk)]));          \
    r7 = __fadd_rn(r7, __fmul_rn(v[8 + (blk)], v[8 + (blk)]))
    VQ_ACC8(8); VQ_ACC8(16); VQ_ACC8(24); VQ_ACC8(32); VQ_ACC8(40); VQ_ACC8(48);
#undef VQ_ACC8
    float tA  = __fadd_rn(__fadd_rn(r0, r1), __fadd_rn(r2, r3));
    float tB  = __fadd_rn(__fadd_rn(r4, r5), __fadd_rn(r6, r7));
    float res = __fadd_rn(tA, tB);
    res = __fadd_rn(res, __fmul_rn(v[57], v[57]));
    res = __fadd_rn(res, __fmul_rn(v[58], v[58]));
    res = __fadd_rn(res, __fmul_rn(v[59], v[59]));
    res = __fadd_rn(res, __fmul_rn(v[60], v[60]));
    res = __fadd_rn(res, __fmul_rn(v[61], v[61]));
    res = __fadd_rn(res, __fmul_rn(v[62], v[62]));
    res = __fadd_rn(res, __fmul_rn(v[63], v[63]));
    return __fadd_rn(__fmul_rn(v[0], v[0]), res);
}

__global__ __launch_bounds__(256) void vq_prep(const float* __restrict__ cb,
                                               float* __restrict__ scn,
                                               float* __restrict__ loss_slot)
{
    int j = blockIdx.x * 256 + threadIdx.x;
    if (j < N_E) {
        const float* c = cb + (size_t)j * E_DIM;
        f32x64 cr;
#pragma unroll
        for (int k = 0; k < E_DIM; k += 4) {
            float4 v = *(const float4*)(c + k);
            cr[k] = v.x; cr[k + 1] = v.y; cr[k + 2] = v.z; cr[k + 3] = v.w;
        }
        scn[j] = np_sumsq64_v(cr);
    }
    if (blockIdx.x == 0 && threadIdx.x == 0) *loss_slot = 0.f;
}

// ---------------------------------------------------------------------------
// Main (r6 structure + 2-way j-split for occupancy). Each token is handled
// by TWO threads: half 0 scans j in [0,512), half 1 scans [512,1024); both
// hold the same x-row. Grid supplies 2048 threads/CU = 8 waves/SIMD (r3/r6's
// 1-thread/token grid capped the CU at 4 waves/SIMD -> 72% VALUBusy at 42%
// occupancy; doubling resident waves hides SMEM/spill latency).
// Merge preserves numpy first-occurrence EXACTLY: hi-half indices are all
// larger, so a tie keeps the lo half (strict <).
// Bit-exact np f32 pipeline (frozen from passing r3/r6):
//   m_j: single fmaf chain, k = 0..63 strictly ascending
//   d_j = f32( f32(sx + scn_j) - f32(2*m_j) ); argmin strict <, j ascending.
// ---------------------------------------------------------------------------
__global__ __launch_bounds__(BLK)
void vq_main(const float* __restrict__ x,
             const float* __restrict__ cb,
             const float* __restrict__ scn,
             float* __restrict__ xq_out,
             float* __restrict__ loss_out,
             float* __restrict__ idx_out)
{
    __shared__ float md[TPB];
    __shared__ int   mi[TPB];
    __shared__ float red[4];

    const int t    = threadIdx.x;
    const int half = t >> 7;                    // 0: j<512, 1: j>=512
    const int lt   = t & (TPB - 1);             // token slot in block
    const int tok  = blockIdx.x * TPB + lt;
    const int jb   = half * JSPL;

    f32x64 xr;
    {
        const float* xrow = x + (size_t)tok * E_DIM;
#pragma unroll
        for (int k = 0; k < E_DIM; k += 4) {
            float4 v = *(const float4*)(xrow + k);
            xr[k] = v.x; xr[k + 1] = v.y; xr[k + 2] = v.z; xr[k + 3] = v.w;
        }
    }

    const float sx = np_sumsq64_v(xr);

    float dmin = FLT_MAX;
    int   imin = jb;

    for (int j = jb; j < jb + JSPL; j += 2) {
        const float* c0 = cb + (size_t)j * E_DIM;   // wave-uniform address
        const float* c1 = c0 + E_DIM;
        float m0 = 0.f, m1 = 0.f;                   // sequential k-chains
#pragma unroll
        for (int k = 0; k < E_DIM; ++k) {
            m0 = fmaf(xr[k], c0[k], m0);
            m1 = fmaf(xr[k], c1[k], m1);
        }
        float d0 = __fsub_rn(__fadd_rn(sx, scn[j    ]), __fmul_rn(2.0f, m0));
        float d1 = __fsub_rn(__fadd_rn(sx, scn[j + 1]), __fmul_rn(2.0f, m1));
        if (d0 < dmin) { dmin = d0; imin = j; }
        if (d1 < dmin) { dmin = d1; imin = j + 1; }
    }

    // ---- merge halves: hi writes, lo compares (strict < keeps lo on ties
    //      == global first-occurrence since hi indices are all larger) ----
    if (half) { md[lt] = dmin; mi[lt] = imin; }
    __syncthreads();

    float lsum = 0.f;
    if (!half) {
        float dh = md[lt]; int ih = mi[lt];
        if (dh < dmin) { dmin = dh; imin = ih; }

        // epilogue: gather winning row (L2-hot), write x_q, fused loss
        const float* cmin = cb + (size_t)imin * E_DIM;  // per-lane address
        float*       xq   = xq_out + (size_t)tok * E_DIM;
#pragma unroll
        for (int k = 0; k < E_DIM; k += 4) {
            float4 cv = *(const float4*)(cmin + k);
            *(float4*)(xq + k) = cv;                    // fwd x_q_st == x_q
            float e0 = cv.x - xr[k    ];
            float e1 = cv.y - xr[k + 1];
            float e2 = cv.z - xr[k + 2];
            float e3 = cv.w - xr[k + 3];
            lsum = fmaf(e0, e0, lsum);
            lsum = fmaf(e1, e1, lsum);
            lsum = fmaf(e2, e2, lsum);
            lsum = fmaf(e3, e3, lsum);
        }
        idx_out[tok] = (float)imin;   // exact integer in f32
    }

    // Loss: 64-lane shuffle tree (waves 2,3 contribute 0), cross-wave via
    // LDS, one atomic per block.
    for (int m = 1; m < 64; m <<= 1) lsum += __shfl_xor(lsum, m, 64);
    if ((t & 63) == 0) red[t >> 6] = lsum;
    __syncthreads();
    if (t == 0) {
        float part = (red[0] + red[1]) + (red[2] + red[3]);
        const float scale = (1.0f + BETA) / ((float)N_TOK * (float)E_DIM);
        atomicAdd(loss_out, part * scale);
    }
}

extern "C" void kernel_launch(void* const* d_in, const int* in_sizes, int n_in,
                              void* d_out, int out_size, void* d_ws, size_t ws_size,
                              hipStream_t stream)
{
    const float* x  = (const float*)d_in[0];   // [262144, 64] f32
    const float* cb = (const float*)d_in[1];   // [1024, 64]   f32

    float* out  = (float*)d_out;
    float* xq   = out;                              // 262144*64 floats
    float* loss = out + (size_t)N_TOK * E_DIM;      // 1 float
    float* idx  = loss + 1;                         // 262144 floats

    float* scn = (float*)d_ws;                      // 1024 floats scratch

    vq_prep<<<N_E / 256, 256, 0, stream>>>(cb, scn, loss);
    vq_main<<<N_TOK / TPB, BLK, 0, stream>>>(x, cb, scn, xq, loss, idx);
}